// Round 1
// baseline (628.515 us; speedup 1.0000x reference)
//
#include <hip/hip_runtime.h>
#include <stdint.h>

// Problem constants
#define S_LEN   2048
#define BATCH   2
#define DM      1024
#define NHEADS  16
#define HD      64
#define WIN     256
#define MROWS   (BATCH * S_LEN)          // 4096
#define NX      (MROWS * DM)             // 4194304 x elements
#define NW      (DM * DM)                // 1048576 per weight

typedef unsigned short u16;
typedef unsigned int   u32;

using short8  = __attribute__((ext_vector_type(8))) short;   // 8 bf16 (4 VGPRs)
using floatx4 = __attribute__((ext_vector_type(4))) float;   // MFMA acc

__device__ __forceinline__ float bf2f(u16 u) {
    union { u32 u; float f; } v; v.u = ((u32)u) << 16; return v.f;
}
__device__ __forceinline__ float bflo(u32 u) {
    union { u32 u; float f; } v; v.u = u << 16; return v.f;
}
__device__ __forceinline__ float bfhi(u32 u) {
    union { u32 u; float f; } v; v.u = u & 0xffff0000u; return v.f;
}
__device__ __forceinline__ u16 f2bf(float f) {
    union { float f; u32 u; } v; v.f = f;
    u32 u = v.u;
    u += 0x7fffu + ((u >> 16) & 1u);   // RNE
    return (u16)(u >> 16);
}

// ---------------------------------------------------------------------------
// Dtype probe: if the input buffer is really fp32, reading it as bf16 yields
// huge-exponent garbage in the low halves of each float (P~0.42 per sample).
// flag = 0 -> data is bf16 ; flag = 1 -> data is fp32
// ---------------------------------------------------------------------------
__global__ __launch_bounds__(256) void detect_mode(const u16* x, int* flag) {
    __shared__ int sbad;
    int t = threadIdx.x;
    if (t == 0) sbad = 0;
    __syncthreads();
    int bad = 0;
    for (int i = t; i < 4096; i += 256) {
        float v = bf2f(x[i]);
        if (!(fabsf(v) < 1e6f)) bad = 1;   // catches huge / inf / nan
    }
    if (bad) atomicOr(&sbad, 1);
    __syncthreads();
    if (t == 0) flag[0] = sbad;
}

// ---------------------------------------------------------------------------
// Normalize all inputs into canonical bf16 buffers in workspace.
// Wq/Wk/Wv are concatenated row-wise into wcat [3072][1024].
// ---------------------------------------------------------------------------
__global__ __launch_bounds__(256) void normalize_inputs(
        const void* x, const void* wq, const void* wk, const void* wv, const void* wo,
        u16* xb, u16* wcat, u16* wob, const int* flag) {
    const int mode = flag[0];
    const int total = NX + 4 * NW;
    for (int i = blockIdx.x * blockDim.x + threadIdx.x; i < total;
         i += gridDim.x * blockDim.x) {
        const void* src; u16* dst; int li;
        if (i < NX)              { src = x;  dst = xb;            li = i; }
        else if (i < NX + NW)    { src = wq; dst = wcat;          li = i - NX; }
        else if (i < NX + 2*NW)  { src = wk; dst = wcat + NW;     li = i - NX - NW; }
        else if (i < NX + 3*NW)  { src = wv; dst = wcat + 2*NW;   li = i - NX - 2*NW; }
        else                     { src = wo; dst = wob;           li = i - NX - 3*NW; }
        u16 v = mode ? f2bf(((const float*)src)[li]) : ((const u16*)src)[li];
        dst[li] = v;
    }
}

// ---------------------------------------------------------------------------
// GEMM  C[M,N] = A[M,K] * B[N,K]^T   (both bf16, fp32 accumulate)
// Per-wave 32x32 tile via 2x2 mfma_f32_16x16x32_bf16 frags; block = 4 waves
// = 64x64 output tile. No LDS (round-0 simplicity). M,N,K multiples of 64.
// final_out: 0 -> always store bf16 ; 1 -> store per *flag (bf16 or fp32)
// ---------------------------------------------------------------------------
__global__ __launch_bounds__(256) void gemm_bt(
        const u16* __restrict__ A, const u16* __restrict__ B, void* __restrict__ C,
        int M, int N, int K, const int* flag, int final_out) {
    const int lane = threadIdx.x & 63;
    const int wave = threadIdx.x >> 6;
    const int wr = wave >> 1, wc = wave & 1;
    const int m_base = blockIdx.x * 64 + wr * 32;
    const int n_base = blockIdx.y * 64 + wc * 32;
    const int m16 = lane & 15;
    const int ko  = (lane >> 4) * 8;

    const short8* pa0 = (const short8*)(A + (size_t)(m_base + m16) * K + ko);
    const short8* pa1 = (const short8*)(A + (size_t)(m_base + 16 + m16) * K + ko);
    const short8* pb0 = (const short8*)(B + (size_t)(n_base + m16) * K + ko);
    const short8* pb1 = (const short8*)(B + (size_t)(n_base + 16 + m16) * K + ko);

    floatx4 acc00 = {0.f, 0.f, 0.f, 0.f};
    floatx4 acc01 = acc00, acc10 = acc00, acc11 = acc00;

    for (int k0 = 0; k0 < K; k0 += 32) {
        short8 a0 = pa0[0]; short8 a1 = pa1[0];
        short8 b0 = pb0[0]; short8 b1 = pb1[0];
        pa0 += 4; pa1 += 4; pb0 += 4; pb1 += 4;
        acc00 = __builtin_amdgcn_mfma_f32_16x16x32_bf16(a0, b0, acc00, 0, 0, 0);
        acc01 = __builtin_amdgcn_mfma_f32_16x16x32_bf16(a0, b1, acc01, 0, 0, 0);
        acc10 = __builtin_amdgcn_mfma_f32_16x16x32_bf16(a1, b0, acc10, 0, 0, 0);
        acc11 = __builtin_amdgcn_mfma_f32_16x16x32_bf16(a1, b1, acc11, 0, 0, 0);
    }

    // C/D layout: col = lane&15, row = (lane>>4)*4 + reg   [m89/m91 verified]
    const int rl = (lane >> 4) * 4;
    const int cl = lane & 15;
    const int mode = final_out ? flag[0] : 0;
    floatx4 accs[2][2] = {{acc00, acc01}, {acc10, acc11}};
    for (int i = 0; i < 2; ++i) {
        for (int j = 0; j < 2; ++j) {
            for (int r = 0; r < 4; ++r) {
                int row = m_base + i * 16 + rl + r;
                int col = n_base + j * 16 + cl;
                float v = accs[i][j][r];
                size_t idx = (size_t)row * N + col;
                if (mode) ((float*)C)[idx] = v;
                else      ((u16*)C)[idx]   = f2bf(v);
            }
        }
    }
}

// ---------------------------------------------------------------------------
// Sliding-window attention. One block = (b, h, 16-query tile).
// Key window per tile: [q0-255, q0+15] -> <= 271 keys, fully staged in LDS,
// so a plain (non-online) softmax over the whole row is exact.
// QKV layout: [4096][3072] with cols [0,1024)=Q, [1024,2048)=K, [2048,3072)=V,
// col within = h*64 + d.
// ---------------------------------------------------------------------------
__global__ __launch_bounds__(256) void attn_window(
        const u16* __restrict__ QKV, u16* __restrict__ O) {
    const int bh = blockIdx.x;
    const int b  = bh >> 4, h = bh & 15;
    const int q0 = blockIdx.y * 16;
    int ks = q0 - (WIN - 1); if (ks < 0) ks = 0;
    const int ke = q0 + 15;
    const int count = ke - ks + 1;    // <= 271
    const int t = threadIdx.x;

    __shared__ __align__(16) float sQ[16][68];
    __shared__ __align__(16) u16   sK[272][68];
    __shared__ __align__(16) u16   sV[272][68];
    __shared__ __align__(16) float sS[16][273];
    __shared__ float red[16][16];
    __shared__ float sM[16], sR[16];

    const u16* Qb = QKV + (size_t)b * S_LEN * 3072 + h * 64;
    const u16* Kb = Qb + 1024;
    const u16* Vb = Qb + 2048;

    // stage Q (as fp32) and K/V (bf16) tiles
    for (int i = t; i < 16 * 64; i += 256) {
        int q = i >> 6, d = i & 63;
        sQ[q][d] = bf2f(Qb[(size_t)(q0 + q) * 3072 + d]);
    }
    for (int i = t; i < count * 64; i += 256) {
        int r = i >> 6, d = i & 63;
        size_t off = (size_t)(ks + r) * 3072 + d;
        sK[r][d] = Kb[off];
        sV[r][d] = Vb[off];
    }
    __syncthreads();

    const int q  = t >> 4;      // query row handled by this thread
    const int jl = t & 15;      // lane within the 16-thread row group
    const int sq = q0 + q;

    // scores
    for (int j = jl; j < count; j += 16) {
        int kg = ks + j;
        float acc = 0.f;
        #pragma unroll
        for (int d = 0; d < 64; d += 4) {
            float4 qv = *(const float4*)&sQ[q][d];
            uint2  kv = *(const uint2*)&sK[j][d];
            acc += qv.x * bflo(kv.x);
            acc += qv.y * bfhi(kv.x);
            acc += qv.z * bflo(kv.y);
            acc += qv.w * bfhi(kv.y);
        }
        bool valid = (kg >= sq - (WIN - 1)) && (kg <= sq);
        sS[q][j] = valid ? acc * 0.125f : -1e30f;
    }
    __syncthreads();

    // softmax: row max
    float pm = -1e30f;
    for (int j = jl; j < count; j += 16) pm = fmaxf(pm, sS[q][j]);
    red[q][jl] = pm;
    __syncthreads();
    if (jl == 0) {
        float m = red[q][0];
        #pragma unroll
        for (int i = 1; i < 16; ++i) m = fmaxf(m, red[q][i]);
        sM[q] = m;
    }
    __syncthreads();
    const float m = sM[q];
    float ps = 0.f;
    for (int j = jl; j < count; j += 16) {
        float e = __expf(sS[q][j] - m);
        sS[q][j] = e;
        ps += e;
    }
    red[q][jl] = ps;
    __syncthreads();
    if (jl == 0) {
        float s = 0.f;
        #pragma unroll
        for (int i = 1; i < 16; ++i) red[q][0] += 0.f;  // no-op keep simple
        s = 0.f;
        #pragma unroll
        for (int i = 0; i < 16; ++i) s += red[q][i];
        sR[q] = 1.0f / s;
    }
    __syncthreads();

    // P*V : thread (q, jl) accumulates output dims d0..d0+3 for query q
    const int d0 = jl * 4;
    float o0 = 0.f, o1 = 0.f, o2 = 0.f, o3 = 0.f;
    for (int j = 0; j < count; ++j) {
        float p = sS[q][j];
        uint2 vv = *(const uint2*)&sV[j][d0];
        o0 += p * bflo(vv.x);
        o1 += p * bfhi(vv.x);
        o2 += p * bflo(vv.y);
        o3 += p * bfhi(vv.y);
    }
    const float r = sR[q];
    size_t ob = ((size_t)(b * S_LEN + q0 + q)) * DM + h * 64 + d0;
    O[ob + 0] = f2bf(o0 * r);
    O[ob + 1] = f2bf(o1 * r);
    O[ob + 2] = f2bf(o2 * r);
    O[ob + 3] = f2bf(o3 * r);
}

// ---------------------------------------------------------------------------
extern "C" void kernel_launch(void* const* d_in, const int* in_sizes, int n_in,
                              void* d_out, int out_size, void* d_ws, size_t ws_size,
                              hipStream_t stream) {
    char* ws = (char*)d_ws;
    int* flag = (int*)ws;
    u16* xb   = (u16*)(ws + 1024);
    u16* wcat = xb   + (size_t)NX;          //  3*NW elems
    u16* wob  = wcat + (size_t)3 * NW;      //  NW elems
    u16* qkv  = wob  + (size_t)NW;          //  MROWS*3*DM elems
    u16* ob   = qkv  + (size_t)MROWS * 3 * DM;  // NX elems
    // total ws use: 1024 + 2*(NX + 4*NW + 3*NX + NX) ~= 48 MB

    detect_mode<<<1, 256, 0, stream>>>((const u16*)d_in[0], flag);
    normalize_inputs<<<8192, 256, 0, stream>>>(
        d_in[0], d_in[1], d_in[2], d_in[3], d_in[4], xb, wcat, wob, flag);
    // QKV = x * Wcat^T : [4096,1024] x [3072,1024]^T -> [4096,3072]
    gemm_bt<<<dim3(64, 48), 256, 0, stream>>>(xb, wcat, qkv, MROWS, 3 * DM, DM, flag, 0);
    // attention -> ob [4096,1024]
    attn_window<<<dim3(BATCH * NHEADS, S_LEN / 16), 256, 0, stream>>>(qkv, ob);
    // out = ob * Wo^T -> d_out [4096,1024]
    gemm_bt<<<dim3(64, 16), 256, 0, stream>>>(ob, wob, d_out, MROWS, DM, DM, flag, 1);
}

// Round 2
// 352.672 us; speedup vs baseline: 1.7821x; 1.7821x over previous
//
#include <hip/hip_runtime.h>
#include <stdint.h>

// Problem constants
#define S_LEN   2048
#define BATCH   2
#define DM      1024
#define NHEADS  16
#define HD      64
#define WIN     256
#define MROWS   (BATCH * S_LEN)          // 4096
#define NX      (MROWS * DM)             // 4194304 x elements
#define NW      (DM * DM)                // 1048576 per weight

typedef unsigned short u16;
typedef unsigned int   u32;

using short8  = __attribute__((ext_vector_type(8))) short;   // 8 bf16 (4 VGPRs)
using floatx4 = __attribute__((ext_vector_type(4))) float;   // MFMA acc

__device__ __forceinline__ float bf2f(u16 u) {
    union { u32 u; float f; } v; v.u = ((u32)u) << 16; return v.f;
}
__device__ __forceinline__ u16 f2bf(float f) {
    union { float f; u32 u; } v; v.f = f;
    u32 u = v.u;
    u += 0x7fffu + ((u >> 16) & 1u);   // RNE
    return (u16)(u >> 16);
}

// ---------------------------------------------------------------------------
// Dtype probe: flag = 0 -> bf16 inputs ; flag = 1 -> fp32 inputs
// ---------------------------------------------------------------------------
__global__ __launch_bounds__(256) void detect_mode(const u16* x, int* flag) {
    __shared__ int sbad;
    int t = threadIdx.x;
    if (t == 0) sbad = 0;
    __syncthreads();
    int bad = 0;
    for (int i = t; i < 4096; i += 256) {
        float v = bf2f(x[i]);
        if (!(fabsf(v) < 1e6f)) bad = 1;
    }
    if (bad) atomicOr(&sbad, 1);
    __syncthreads();
    if (t == 0) flag[0] = sbad;
}

// ---------------------------------------------------------------------------
// Normalize inputs into canonical bf16 buffers. Wq/Wk/Wv concat -> wcat.
// ---------------------------------------------------------------------------
__global__ __launch_bounds__(256) void normalize_inputs(
        const void* x, const void* wq, const void* wk, const void* wv, const void* wo,
        u16* xb, u16* wcat, u16* wob, const int* flag) {
    const int mode = flag[0];
    const int total = NX + 4 * NW;
    for (int i = blockIdx.x * blockDim.x + threadIdx.x; i < total;
         i += gridDim.x * blockDim.x) {
        const void* src; u16* dst; int li;
        if (i < NX)              { src = x;  dst = xb;            li = i; }
        else if (i < NX + NW)    { src = wq; dst = wcat;          li = i - NX; }
        else if (i < NX + 2*NW)  { src = wk; dst = wcat + NW;     li = i - NX - NW; }
        else if (i < NX + 3*NW)  { src = wv; dst = wcat + 2*NW;   li = i - NX - 2*NW; }
        else                     { src = wo; dst = wob;           li = i - NX - 3*NW; }
        u16 v = mode ? f2bf(((const float*)src)[li]) : ((const u16*)src)[li];
        dst[li] = v;
    }
}

// ---------------------------------------------------------------------------
// GEMM  C[M,N] = A[M,K] * B[N,K]^T  (unchanged from R0 — next round's target)
// ---------------------------------------------------------------------------
__global__ __launch_bounds__(256) void gemm_bt(
        const u16* __restrict__ A, const u16* __restrict__ B, void* __restrict__ C,
        int M, int N, int K, const int* flag, int final_out) {
    const int lane = threadIdx.x & 63;
    const int wave = threadIdx.x >> 6;
    const int wr = wave >> 1, wc = wave & 1;
    const int m_base = blockIdx.x * 64 + wr * 32;
    const int n_base = blockIdx.y * 64 + wc * 32;
    const int m16 = lane & 15;
    const int ko  = (lane >> 4) * 8;

    const short8* pa0 = (const short8*)(A + (size_t)(m_base + m16) * K + ko);
    const short8* pa1 = (const short8*)(A + (size_t)(m_base + 16 + m16) * K + ko);
    const short8* pb0 = (const short8*)(B + (size_t)(n_base + m16) * K + ko);
    const short8* pb1 = (const short8*)(B + (size_t)(n_base + 16 + m16) * K + ko);

    floatx4 acc00 = {0.f, 0.f, 0.f, 0.f};
    floatx4 acc01 = acc00, acc10 = acc00, acc11 = acc00;

    for (int k0 = 0; k0 < K; k0 += 32) {
        short8 a0 = pa0[0]; short8 a1 = pa1[0];
        short8 b0 = pb0[0]; short8 b1 = pb1[0];
        pa0 += 4; pa1 += 4; pb0 += 4; pb1 += 4;
        acc00 = __builtin_amdgcn_mfma_f32_16x16x32_bf16(a0, b0, acc00, 0, 0, 0);
        acc01 = __builtin_amdgcn_mfma_f32_16x16x32_bf16(a0, b1, acc01, 0, 0, 0);
        acc10 = __builtin_amdgcn_mfma_f32_16x16x32_bf16(a1, b0, acc10, 0, 0, 0);
        acc11 = __builtin_amdgcn_mfma_f32_16x16x32_bf16(a1, b1, acc11, 0, 0, 0);
    }

    const int rl = (lane >> 4) * 4;
    const int cl = lane & 15;
    const int mode = final_out ? flag[0] : 0;
    floatx4 accs[2][2] = {{acc00, acc01}, {acc10, acc11}};
    for (int i = 0; i < 2; ++i) {
        for (int j = 0; j < 2; ++j) {
            for (int r = 0; r < 4; ++r) {
                int row = m_base + i * 16 + rl + r;
                int col = n_base + j * 16 + cl;
                float v = accs[i][j][r];
                size_t idx = (size_t)row * N + col;
                if (mode) ((float*)C)[idx] = v;
                else      ((u16*)C)[idx]   = f2bf(v);
            }
        }
    }
}

// ---------------------------------------------------------------------------
// MFMA flash-style sliding-window attention.
// Block = 512 threads = 8 waves = 128 queries of one (b,h).
// Staged in LDS: K rows [384][72] bf16, V transposed [64][392] bf16.
// Each wave: 16 queries, online softmax over 9 chunks of 32 keys.
// Fragment layouts (verified m89/m74): A/B [m|n]=lane&15, k=quad*8+j;
// C/D col=lane&15, row=quad*4+reg.
// ---------------------------------------------------------------------------
#define KSTG 384
#define KPAD 72
#define VPAD 392

__global__ __launch_bounds__(512) void attn_mfma(
        const u16* __restrict__ QKV, u16* __restrict__ O) {
    __shared__ __align__(16) u16 sK[KSTG][KPAD];     // 55.3 KB
    __shared__ __align__(16) u16 sVt[64][VPAD];      // 50.2 KB
    __shared__ __align__(16) u16 sP[8][2][16][40];   // 20.5 KB

    const int bh = blockIdx.x;
    const int b  = bh >> 4, h = bh & 15;
    const int q0 = blockIdx.y * 128;
    const int kb0 = q0 - (WIN - 1);                  // may be negative
    const int tid = threadIdx.x;
    const u16* base = QKV + (size_t)b * S_LEN * 3072;

    // ---- stage K (row-major) and V (transposed) ----
    for (int i = tid; i < KSTG * 8; i += 512) {
        int row = i >> 3, seg = i & 7;
        int kg = kb0 + row;
        uint4 kv = {0u, 0u, 0u, 0u}, vv = {0u, 0u, 0u, 0u};
        if (kg >= 0 && kg < S_LEN) {
            const u16* rp = base + (size_t)kg * 3072 + h * 64 + seg * 8;
            kv = *(const uint4*)(rp + 1024);
            vv = *(const uint4*)(rp + 2048);
        }
        *(uint4*)&sK[row][seg * 8] = kv;
        const u16* vp = (const u16*)&vv;
        #pragma unroll
        for (int t2 = 0; t2 < 8; ++t2) sVt[seg * 8 + t2][row] = vp[t2];
    }
    __syncthreads();

    const int wave = tid >> 6, lane = tid & 63;
    const int n16 = lane & 15, quad = lane >> 4;
    const int sqb = q0 + wave * 16;          // wave's first query
    const int sq_r0 = sqb + quad * 4;        // this lane's first acc row

    // Q A-fragments (d 0-31, 32-63), loaded once from global
    const u16* qrow = base + (size_t)(sqb + n16) * 3072 + h * 64;
    short8 aq0 = *(const short8*)(qrow + quad * 8);
    short8 aq1 = *(const short8*)(qrow + 32 + quad * 8);

    floatx4 o0 = {0.f,0.f,0.f,0.f}, o1 = o0, o2 = o0, o3 = o0;
    float m[4] = {-1e30f, -1e30f, -1e30f, -1e30f};
    float l[4] = {0.f, 0.f, 0.f, 0.f};
    const int c0 = wave >> 1;                // first 32-key chunk for this wave

    for (int cc = 0; cc < 9; ++cc) {
        const int krel = (c0 + cc) * 32;
        // QK^T: two 16-key tiles, K=64 contraction in two chained MFMAs
        short8 bk00 = *(const short8*)&sK[krel + n16][quad * 8];
        short8 bk01 = *(const short8*)&sK[krel + n16][32 + quad * 8];
        short8 bk10 = *(const short8*)&sK[krel + 16 + n16][quad * 8];
        short8 bk11 = *(const short8*)&sK[krel + 16 + n16][32 + quad * 8];
        floatx4 z = {0.f, 0.f, 0.f, 0.f};
        floatx4 s0 = __builtin_amdgcn_mfma_f32_16x16x32_bf16(aq0, bk00, z, 0, 0, 0);
        s0 = __builtin_amdgcn_mfma_f32_16x16x32_bf16(aq1, bk01, s0, 0, 0, 0);
        floatx4 s1 = __builtin_amdgcn_mfma_f32_16x16x32_bf16(aq0, bk10, z, 0, 0, 0);
        s1 = __builtin_amdgcn_mfma_f32_16x16x32_bf16(aq1, bk11, s1, 0, 0, 0);

        const int kg0 = kb0 + krel + n16;
        const int kg1 = kg0 + 16;
        float alpha[4], p0[4], p1[4];
        #pragma unroll
        for (int r = 0; r < 4; ++r) {
            int sq = sq_r0 + r;
            int lo = sq - (WIN - 1); if (lo < 0) lo = 0;
            float v0 = (kg0 >= lo && kg0 <= sq) ? s0[r] * 0.125f : -1e30f;
            float v1 = (kg1 >= lo && kg1 <= sq) ? s1[r] * 0.125f : -1e30f;
            float mc = fmaxf(v0, v1);
            mc = fmaxf(mc, __shfl_xor(mc, 1));
            mc = fmaxf(mc, __shfl_xor(mc, 2));
            mc = fmaxf(mc, __shfl_xor(mc, 4));
            mc = fmaxf(mc, __shfl_xor(mc, 8));
            float mn = fmaxf(m[r], mc);
            alpha[r] = __expf(m[r] - mn);
            m[r] = mn;
            p0[r] = __expf(v0 - mn);
            p1[r] = __expf(v1 - mn);
            float rs = p0[r] + p1[r];
            rs += __shfl_xor(rs, 1);
            rs += __shfl_xor(rs, 2);
            rs += __shfl_xor(rs, 4);
            rs += __shfl_xor(rs, 8);
            l[r] = l[r] * alpha[r] + rs;
        }
        #pragma unroll
        for (int r = 0; r < 4; ++r) {
            o0[r] *= alpha[r]; o1[r] *= alpha[r];
            o2[r] *= alpha[r]; o3[r] *= alpha[r];
        }
        // P (C-layout) -> bf16 -> LDS -> re-read in A-layout
        u16* pw = &sP[wave][cc & 1][0][0];
        #pragma unroll
        for (int r = 0; r < 4; ++r) {
            pw[(quad * 4 + r) * 40 + n16]      = f2bf(p0[r]);
            pw[(quad * 4 + r) * 40 + 16 + n16] = f2bf(p1[r]);
        }
        asm volatile("s_waitcnt lgkmcnt(0)" ::: "memory");
        short8 pa  = *(const short8*)&pw[n16 * 40 + quad * 8];
        short8 bv0 = *(const short8*)&sVt[n16]     [krel + quad * 8];
        short8 bv1 = *(const short8*)&sVt[16 + n16][krel + quad * 8];
        short8 bv2 = *(const short8*)&sVt[32 + n16][krel + quad * 8];
        short8 bv3 = *(const short8*)&sVt[48 + n16][krel + quad * 8];
        o0 = __builtin_amdgcn_mfma_f32_16x16x32_bf16(pa, bv0, o0, 0, 0, 0);
        o1 = __builtin_amdgcn_mfma_f32_16x16x32_bf16(pa, bv1, o1, 0, 0, 0);
        o2 = __builtin_amdgcn_mfma_f32_16x16x32_bf16(pa, bv2, o2, 0, 0, 0);
        o3 = __builtin_amdgcn_mfma_f32_16x16x32_bf16(pa, bv3, o3, 0, 0, 0);
    }

    // epilogue: normalize by l, store bf16
    #pragma unroll
    for (int r = 0; r < 4; ++r) {
        float rl = 1.0f / l[r];
        size_t ro = ((size_t)(b * S_LEN + sq_r0 + r)) * DM + h * 64 + n16;
        O[ro]      = f2bf(o0[r] * rl);
        O[ro + 16] = f2bf(o1[r] * rl);
        O[ro + 32] = f2bf(o2[r] * rl);
        O[ro + 48] = f2bf(o3[r] * rl);
    }
}

// ---------------------------------------------------------------------------
extern "C" void kernel_launch(void* const* d_in, const int* in_sizes, int n_in,
                              void* d_out, int out_size, void* d_ws, size_t ws_size,
                              hipStream_t stream) {
    char* ws = (char*)d_ws;
    int* flag = (int*)ws;
    u16* xb   = (u16*)(ws + 1024);
    u16* wcat = xb   + (size_t)NX;
    u16* wob  = wcat + (size_t)3 * NW;
    u16* qkv  = wob  + (size_t)NW;
    u16* ob   = qkv  + (size_t)MROWS * 3 * DM;

    detect_mode<<<1, 256, 0, stream>>>((const u16*)d_in[0], flag);
    normalize_inputs<<<8192, 256, 0, stream>>>(
        d_in[0], d_in[1], d_in[2], d_in[3], d_in[4], xb, wcat, wob, flag);
    // QKV = x * Wcat^T : [4096,1024] x [3072,1024]^T -> [4096,3072]
    gemm_bt<<<dim3(64, 48), 256, 0, stream>>>(xb, wcat, qkv, MROWS, 3 * DM, DM, flag, 0);
    // attention -> ob [4096,1024]
    attn_mfma<<<dim3(BATCH * NHEADS, S_LEN / 128), 512, 0, stream>>>(qkv, ob);
    // out = ob * Wo^T -> d_out [4096,1024]
    gemm_bt<<<dim3(64, 16), 256, 0, stream>>>(ob, wob, d_out, MROWS, DM, DM, flag, 1);
}

// Round 3
// 189.018 us; speedup vs baseline: 3.3252x; 1.8658x over previous
//
#include <hip/hip_runtime.h>
#include <stdint.h>

// Problem constants
#define S_LEN   2048
#define BATCH   2
#define DM      1024
#define NHEADS  16
#define HD      64
#define WIN     256
#define MROWS   (BATCH * S_LEN)          // 4096
#define NX      (MROWS * DM)             // 4194304 x elements
#define NW      (DM * DM)                // 1048576 per weight

typedef unsigned short u16;
typedef unsigned int   u32;

using short8  = __attribute__((ext_vector_type(8))) short;   // 8 bf16 (4 VGPRs)
using floatx4 = __attribute__((ext_vector_type(4))) float;   // MFMA acc

__device__ __forceinline__ float bf2f(u16 u) {
    union { u32 u; float f; } v; v.u = ((u32)u) << 16; return v.f;
}
__device__ __forceinline__ u16 f2bf(float f) {
    union { float f; u32 u; } v; v.f = f;
    u32 u = v.u;
    u += 0x7fffu + ((u >> 16) & 1u);   // RNE
    return (u16)(u >> 16);
}

// async global->LDS, 16B per lane. LDS dest = wave-uniform base + lane*16.
__device__ __forceinline__ void load_lds16(const void* g, void* l) {
    __builtin_amdgcn_global_load_lds(
        (__attribute__((address_space(1))) void*)(uintptr_t)g,
        (__attribute__((address_space(3))) void*)(unsigned int)(uintptr_t)l,
        16, 0, 0);
}

// ---------------------------------------------------------------------------
// Dtype probe: flag = 0 -> bf16 inputs ; flag = 1 -> fp32 inputs
// ---------------------------------------------------------------------------
__global__ __launch_bounds__(256) void detect_mode(const u16* x, int* flag) {
    __shared__ int sbad;
    int t = threadIdx.x;
    if (t == 0) sbad = 0;
    __syncthreads();
    int bad = 0;
    for (int i = t; i < 4096; i += 256) {
        float v = bf2f(x[i]);
        if (!(fabsf(v) < 1e6f)) bad = 1;
    }
    if (bad) atomicOr(&sbad, 1);
    __syncthreads();
    if (t == 0) flag[0] = sbad;
}

// ---------------------------------------------------------------------------
// fp32-mode only: convert inputs to bf16 (bf16 mode: early exit, GEMMs read
// the raw d_in pointers directly).
// ---------------------------------------------------------------------------
__global__ __launch_bounds__(256) void normalize_inputs(
        const void* x, const void* wq, const void* wk, const void* wv, const void* wo,
        u16* xb, u16* wcat, u16* wob, const int* flag) {
    if (flag[0] == 0) return;
    const int total = NX + 4 * NW;
    for (int i = blockIdx.x * blockDim.x + threadIdx.x; i < total;
         i += gridDim.x * blockDim.x) {
        const void* src; u16* dst; int li;
        if (i < NX)              { src = x;  dst = xb;            li = i; }
        else if (i < NX + NW)    { src = wq; dst = wcat;          li = i - NX; }
        else if (i < NX + 2*NW)  { src = wk; dst = wcat + NW;     li = i - NX - NW; }
        else if (i < NX + 3*NW)  { src = wv; dst = wcat + 2*NW;   li = i - NX - 2*NW; }
        else                     { src = wo; dst = wob;           li = i - NX - 3*NW; }
        dst[li] = f2bf(((const float*)src)[li]);
    }
}

// ---------------------------------------------------------------------------
// m97-style GEMM  C[M,N] = A[M,K] * B[N,K]^T  (bf16 in, fp32 acc)
// 128x128 tile, BK=32, 256 threads (4 waves, each 64x64 quadrant, 4x4 frags).
// Staging via global_load_lds width=16; LDS [128][32] row-major UNPADDED so
// the wave-uniform-base + lane*16 destination matches the global lane order.
// B selection: bf16 mode -> one of {B0,B1,B2} by column-third (raw d_in
// weights); fp32 mode -> Bnorm (+ third*NW). Requires M%128==N%128==K%32==0.
// ---------------------------------------------------------------------------
#define BM 128
#define BN 128
#define BK 32

__global__ __launch_bounds__(256) void gemm_lds(
        const u16* __restrict__ Araw, const u16* __restrict__ Anorm,
        const u16* __restrict__ B0, const u16* __restrict__ B1,
        const u16* __restrict__ B2, const u16* __restrict__ Bnorm,
        void* __restrict__ C, int M, int N, int K,
        const int* __restrict__ flag, int final_out) {
    __shared__ __align__(16) u16 sA[BM * BK];   // 8 KB
    __shared__ __align__(16) u16 sB[BN * BK];   // 8 KB

    const int mode = flag[0];
    const int tid  = threadIdx.x;
    const int lane = tid & 63, wave = tid >> 6;
    const int m0  = blockIdx.x * BM;
    const int n0g = blockIdx.y * BN;
    const int third = n0g >> 10;                 // which weight (1024-col thirds)
    const u16* A = mode ? Anorm : Araw;
    const u16* B = mode ? (Bnorm + (size_t)third * NW)
                        : (third == 0 ? B0 : (third == 1 ? B1 : B2));
    const int n0 = n0g - third * 1024;           // row within selected weight

    // staging: wave w, issue r covers rows r*64 + w*16 .. +15 (16 rows x 64B)
    const int srow = lane >> 2;                  // row within 16-row group
    const int scol = (lane & 3) * 8;             // element col within BK
    const u16* gA = A + (size_t)(m0 + wave * 16 + srow) * K + scol;
    const u16* gB = B + (size_t)(n0 + wave * 16 + srow) * K + scol;
    u16* lA = sA + wave * 16 * BK;               // wave-uniform LDS base
    u16* lB = sB + wave * 16 * BK;
    const size_t rstep = (size_t)64 * K;

    const int n16 = lane & 15, quad = lane >> 4;
    const int m_off = (wave >> 1) * 64, n_off = (wave & 1) * 64;

    floatx4 acc[4][4] = {};

    for (int k0 = 0; k0 < K; k0 += BK) {
        load_lds16(gA + k0,         lA);
        load_lds16(gA + k0 + rstep, lA + 64 * BK);
        load_lds16(gB + k0,         lB);
        load_lds16(gB + k0 + rstep, lB + 64 * BK);
        __syncthreads();   // drains vmcnt: staged data visible to all waves
        short8 af[4], bfr[4];
        #pragma unroll
        for (int i = 0; i < 4; ++i)
            af[i] = *(const short8*)&sA[(m_off + i * 16 + n16) * BK + quad * 8];
        #pragma unroll
        for (int j = 0; j < 4; ++j)
            bfr[j] = *(const short8*)&sB[(n_off + j * 16 + n16) * BK + quad * 8];
        #pragma unroll
        for (int i = 0; i < 4; ++i) {
            #pragma unroll
            for (int j = 0; j < 4; ++j)
                acc[i][j] = __builtin_amdgcn_mfma_f32_16x16x32_bf16(
                    af[i], bfr[j], acc[i][j], 0, 0, 0);
        }
        __syncthreads();   // all reads done before next overwrite
    }

    // C/D layout: col = lane&15, row = quad*4 + reg
    const int outmode = final_out ? mode : 0;
    #pragma unroll
    for (int i = 0; i < 4; ++i) {
        #pragma unroll
        for (int j = 0; j < 4; ++j) {
            #pragma unroll
            for (int r = 0; r < 4; ++r) {
                int row = m0 + m_off + i * 16 + quad * 4 + r;
                int col = n0g + n_off + j * 16 + n16;
                size_t idx = (size_t)row * N + col;
                float v = acc[i][j][r];
                if (outmode) ((float*)C)[idx] = v;
                else         ((u16*)C)[idx]   = f2bf(v);
            }
        }
    }
}

// ---------------------------------------------------------------------------
// MFMA flash-style sliding-window attention (unchanged from R1).
// Block = 512 threads = 8 waves = 128 queries of one (b,h).
// ---------------------------------------------------------------------------
#define KSTG 384
#define KPAD 72
#define VPAD 392

__global__ __launch_bounds__(512) void attn_mfma(
        const u16* __restrict__ QKV, u16* __restrict__ O) {
    __shared__ __align__(16) u16 sK[KSTG][KPAD];     // 55.3 KB
    __shared__ __align__(16) u16 sVt[64][VPAD];      // 50.2 KB
    __shared__ __align__(16) u16 sP[8][2][16][40];   // 20.5 KB

    const int bh = blockIdx.x;
    const int b  = bh >> 4, h = bh & 15;
    const int q0 = blockIdx.y * 128;
    const int kb0 = q0 - (WIN - 1);
    const int tid = threadIdx.x;
    const u16* base = QKV + (size_t)b * S_LEN * 3072;

    for (int i = tid; i < KSTG * 8; i += 512) {
        int row = i >> 3, seg = i & 7;
        int kg = kb0 + row;
        uint4 kv = {0u, 0u, 0u, 0u}, vv = {0u, 0u, 0u, 0u};
        if (kg >= 0 && kg < S_LEN) {
            const u16* rp = base + (size_t)kg * 3072 + h * 64 + seg * 8;
            kv = *(const uint4*)(rp + 1024);
            vv = *(const uint4*)(rp + 2048);
        }
        *(uint4*)&sK[row][seg * 8] = kv;
        const u16* vp = (const u16*)&vv;
        #pragma unroll
        for (int t2 = 0; t2 < 8; ++t2) sVt[seg * 8 + t2][row] = vp[t2];
    }
    __syncthreads();

    const int wave = tid >> 6, lane = tid & 63;
    const int n16 = lane & 15, quad = lane >> 4;
    const int sqb = q0 + wave * 16;
    const int sq_r0 = sqb + quad * 4;

    const u16* qrow = base + (size_t)(sqb + n16) * 3072 + h * 64;
    short8 aq0 = *(const short8*)(qrow + quad * 8);
    short8 aq1 = *(const short8*)(qrow + 32 + quad * 8);

    floatx4 o0 = {0.f,0.f,0.f,0.f}, o1 = o0, o2 = o0, o3 = o0;
    float m[4] = {-1e30f, -1e30f, -1e30f, -1e30f};
    float l[4] = {0.f, 0.f, 0.f, 0.f};
    const int c0 = wave >> 1;

    for (int cc = 0; cc < 9; ++cc) {
        const int krel = (c0 + cc) * 32;
        short8 bk00 = *(const short8*)&sK[krel + n16][quad * 8];
        short8 bk01 = *(const short8*)&sK[krel + n16][32 + quad * 8];
        short8 bk10 = *(const short8*)&sK[krel + 16 + n16][quad * 8];
        short8 bk11 = *(const short8*)&sK[krel + 16 + n16][32 + quad * 8];
        floatx4 z = {0.f, 0.f, 0.f, 0.f};
        floatx4 s0 = __builtin_amdgcn_mfma_f32_16x16x32_bf16(aq0, bk00, z, 0, 0, 0);
        s0 = __builtin_amdgcn_mfma_f32_16x16x32_bf16(aq1, bk01, s0, 0, 0, 0);
        floatx4 s1 = __builtin_amdgcn_mfma_f32_16x16x32_bf16(aq0, bk10, z, 0, 0, 0);
        s1 = __builtin_amdgcn_mfma_f32_16x16x32_bf16(aq1, bk11, s1, 0, 0, 0);

        const int kg0 = kb0 + krel + n16;
        const int kg1 = kg0 + 16;
        float alpha[4], p0[4], p1[4];
        #pragma unroll
        for (int r = 0; r < 4; ++r) {
            int sq = sq_r0 + r;
            int lo = sq - (WIN - 1); if (lo < 0) lo = 0;
            float v0 = (kg0 >= lo && kg0 <= sq) ? s0[r] * 0.125f : -1e30f;
            float v1 = (kg1 >= lo && kg1 <= sq) ? s1[r] * 0.125f : -1e30f;
            float mc = fmaxf(v0, v1);
            mc = fmaxf(mc, __shfl_xor(mc, 1));
            mc = fmaxf(mc, __shfl_xor(mc, 2));
            mc = fmaxf(mc, __shfl_xor(mc, 4));
            mc = fmaxf(mc, __shfl_xor(mc, 8));
            float mn = fmaxf(m[r], mc);
            alpha[r] = __expf(m[r] - mn);
            m[r] = mn;
            p0[r] = __expf(v0 - mn);
            p1[r] = __expf(v1 - mn);
            float rs = p0[r] + p1[r];
            rs += __shfl_xor(rs, 1);
            rs += __shfl_xor(rs, 2);
            rs += __shfl_xor(rs, 4);
            rs += __shfl_xor(rs, 8);
            l[r] = l[r] * alpha[r] + rs;
        }
        #pragma unroll
        for (int r = 0; r < 4; ++r) {
            o0[r] *= alpha[r]; o1[r] *= alpha[r];
            o2[r] *= alpha[r]; o3[r] *= alpha[r];
        }
        u16* pw = &sP[wave][cc & 1][0][0];
        #pragma unroll
        for (int r = 0; r < 4; ++r) {
            pw[(quad * 4 + r) * 40 + n16]      = f2bf(p0[r]);
            pw[(quad * 4 + r) * 40 + 16 + n16] = f2bf(p1[r]);
        }
        asm volatile("s_waitcnt lgkmcnt(0)" ::: "memory");
        short8 pa  = *(const short8*)&pw[n16 * 40 + quad * 8];
        short8 bv0 = *(const short8*)&sVt[n16]     [krel + quad * 8];
        short8 bv1 = *(const short8*)&sVt[16 + n16][krel + quad * 8];
        short8 bv2 = *(const short8*)&sVt[32 + n16][krel + quad * 8];
        short8 bv3 = *(const short8*)&sVt[48 + n16][krel + quad * 8];
        o0 = __builtin_amdgcn_mfma_f32_16x16x32_bf16(pa, bv0, o0, 0, 0, 0);
        o1 = __builtin_amdgcn_mfma_f32_16x16x32_bf16(pa, bv1, o1, 0, 0, 0);
        o2 = __builtin_amdgcn_mfma_f32_16x16x32_bf16(pa, bv2, o2, 0, 0, 0);
        o3 = __builtin_amdgcn_mfma_f32_16x16x32_bf16(pa, bv3, o3, 0, 0, 0);
    }

    #pragma unroll
    for (int r = 0; r < 4; ++r) {
        float rl = 1.0f / l[r];
        size_t ro = ((size_t)(b * S_LEN + sq_r0 + r)) * DM + h * 64 + n16;
        O[ro]      = f2bf(o0[r] * rl);
        O[ro + 16] = f2bf(o1[r] * rl);
        O[ro + 32] = f2bf(o2[r] * rl);
        O[ro + 48] = f2bf(o3[r] * rl);
    }
}

// ---------------------------------------------------------------------------
extern "C" void kernel_launch(void* const* d_in, const int* in_sizes, int n_in,
                              void* d_out, int out_size, void* d_ws, size_t ws_size,
                              hipStream_t stream) {
    char* ws = (char*)d_ws;
    int* flag = (int*)ws;
    u16* xb   = (u16*)(ws + 1024);
    u16* wcat = xb   + (size_t)NX;
    u16* wob  = wcat + (size_t)3 * NW;
    u16* qkv  = wob  + (size_t)NW;
    u16* ob   = qkv  + (size_t)MROWS * 3 * DM;

    const u16* xr  = (const u16*)d_in[0];
    const u16* wqr = (const u16*)d_in[1];
    const u16* wkr = (const u16*)d_in[2];
    const u16* wvr = (const u16*)d_in[3];
    const u16* wor = (const u16*)d_in[4];

    detect_mode<<<1, 256, 0, stream>>>(xr, flag);
    normalize_inputs<<<4096, 256, 0, stream>>>(
        d_in[0], d_in[1], d_in[2], d_in[3], d_in[4], xb, wcat, wob, flag);
    // QKV = x * Wcat^T : [4096,1024] x [3072,1024]^T -> [4096,3072]
    gemm_lds<<<dim3(MROWS / BM, 3072 / BN), 256, 0, stream>>>(
        xr, xb, wqr, wkr, wvr, wcat, qkv, MROWS, 3 * DM, DM, flag, 0);
    // attention -> ob [4096,1024]
    attn_mfma<<<dim3(BATCH * NHEADS, S_LEN / 128), 512, 0, stream>>>(qkv, ob);
    // out = ob * Wo^T -> d_out [4096,1024]
    gemm_lds<<<dim3(MROWS / BM, DM / BN), 256, 0, stream>>>(
        ob, ob, wor, wor, wor, wob, d_out, MROWS, DM, DM, flag, 1);
}